// Round 3
// baseline (684.802 us; speedup 1.0000x reference)
//
#include <hip/hip_runtime.h>
#include <hip/hip_bf16.h>

#define H_   32
#define KVH_ 8
#define D_   128
#define DV_  128
#define SEQ_ 1024
#define QKD  (H_*D_)     // 4096 floats per token row of Q
#define KVD  (KVH_*D_)   // 1024 floats per token row of K/V
#define CS_  (0.08838834764831845f * 1.4426950408889634f)  // SCALE*log2(e), folded into Q

typedef __attribute__((ext_vector_type(8))) short bf16x8;
typedef __attribute__((ext_vector_type(4))) float f32x4;
typedef __attribute__((ext_vector_type(4))) unsigned int u32x4;

#if __has_builtin(__builtin_amdgcn_exp2f)
#define EXP2F(x) __builtin_amdgcn_exp2f(x)
#else
#define EXP2F(x) exp2f(x)
#endif

static __device__ __forceinline__ unsigned short f2b(float x) {
    __hip_bfloat16 b = __float2bfloat16(x);
    return __builtin_bit_cast(unsigned short, b);
}
static __device__ __forceinline__ unsigned pk2(float a, float b) {
    return (unsigned)f2b(a) | ((unsigned)f2b(b) << 16);
}

#define PW_STR 40

__global__ __launch_bounds__(256, 4)
void attn_fwd(const float* __restrict__ Q, const float* __restrict__ K,
              const float* __restrict__ V, float* __restrict__ O) {
    // K tile: [32 rows][256B], XOR byte^((row&7)<<4)  -> conflict-free b128 reads
    // V^T tile: [dv=128 rows][64B], XOR byte^((row&3)<<4) -> 8 quads x 8 deep = min
    __shared__ __align__(16) unsigned short KS[2][32 * 128];
    __shared__ __align__(16) unsigned short VT[2][128 * 32];
    __shared__ __align__(16) unsigned short PW[4][16 * PW_STR];

    // grid = B(4)*H(32)*pair(8) = 1024; XCD-bijective swizzle (1024%8==0)
    const int bid = ((int)blockIdx.x & 7) * 128 + ((int)blockIdx.x >> 3);
    const int p   = bid & 7;           // q-tile pair {p, 15-p}: uniform 34 k-tiles/block
    const int h   = (bid >> 3) & 31;
    const int b   = bid >> 8;
    const int kvh = h >> 2;

    const int tid = threadIdx.x;
    const int w   = tid >> 6;
    const int l   = tid & 63;
    const int lo  = l & 15;
    const int g   = l >> 4;

    const int kr_ = tid >> 3;          // K stage row 0..31
    const int kq_ = tid & 7;           // K stage 16-float quarter
    const int sdv = tid & 127;         // V stage dv row
    const int skh = tid >> 7;          // V stage k-half

    const float* Kb = K + ((size_t)(b * SEQ_)) * KVD + kvh * D_;
    const float* Vb = V + ((size_t)(b * SEQ_)) * KVD + kvh * DV_;

    float4 kpre[4];
    float  vpre[16];

    auto stage_load = [&](int t) {
        const float* kp = Kb + ((size_t)(t * 32 + kr_)) * KVD + kq_ * 16;
        kpre[0] = *(const float4*)(kp);
        kpre[1] = *(const float4*)(kp + 4);
        kpre[2] = *(const float4*)(kp + 8);
        kpre[3] = *(const float4*)(kp + 12);
        const float* vp = Vb + ((size_t)(t * 32 + skh * 16)) * KVD + sdv;
#pragma unroll
        for (int e = 0; e < 16; ++e) vpre[e] = vp[(size_t)e * KVD];
    };
    auto stage_write = [&](int d) {
        char* kbase = (char*)KS[d];
        const int kb  = kr_ * 256 + kq_ * 32;
        const int swk = (kr_ & 7) << 4;
        u32x4 ka = { pk2(kpre[0].x, kpre[0].y), pk2(kpre[0].z, kpre[0].w),
                     pk2(kpre[1].x, kpre[1].y), pk2(kpre[1].z, kpre[1].w) };
        u32x4 kc = { pk2(kpre[2].x, kpre[2].y), pk2(kpre[2].z, kpre[2].w),
                     pk2(kpre[3].x, kpre[3].y), pk2(kpre[3].z, kpre[3].w) };
        *(u32x4*)(kbase + (kb ^ swk))        = ka;
        *(u32x4*)(kbase + ((kb + 16) ^ swk)) = kc;
        char* vbase = (char*)VT[d];
        const int swv = (sdv & 3) << 4;
        u32x4 v0 = { pk2(vpre[0], vpre[1]),   pk2(vpre[2], vpre[3]),
                     pk2(vpre[4], vpre[5]),   pk2(vpre[6], vpre[7]) };
        u32x4 v1 = { pk2(vpre[8], vpre[9]),   pk2(vpre[10], vpre[11]),
                     pk2(vpre[12], vpre[13]), pk2(vpre[14], vpre[15]) };
        *(u32x4*)(vbase + sdv * 64 + ((skh * 32) ^ swv))      = v0;
        *(u32x4*)(vbase + sdv * 64 + ((skh * 32 + 16) ^ swv)) = v1;
    };

#pragma unroll 1
    for (int ph = 0; ph < 2; ++ph) {
        const int qt     = ph ? (15 - p) : p;
        const int ntiles = 2 * qt + 2;
        const int qw0    = qt * 64 + w * 16;
        const int jmaxw  = (qw0 + 15) >> 5;

        // Q fragments pre-scaled by SCALE*log2(e): row=lo, d=32c+8g+e
        const float* Qb = Q + ((size_t)(b * SEQ_ + qw0 + lo)) * QKD + h * D_;
        bf16x8 qf[4];
#pragma unroll
        for (int c = 0; c < 4; ++c) {
            const float* qp = Qb + c * 32 + g * 8;
            float4 x0 = *(const float4*)(qp);
            float4 x1 = *(const float4*)(qp + 4);
            bf16x8 f;
            f[0] = f2b(x0.x * CS_); f[1] = f2b(x0.y * CS_);
            f[2] = f2b(x0.z * CS_); f[3] = f2b(x0.w * CS_);
            f[4] = f2b(x1.x * CS_); f[5] = f2b(x1.y * CS_);
            f[6] = f2b(x1.z * CS_); f[7] = f2b(x1.w * CS_);
            qf[c] = f;
        }

        float m_[4], lsum[4];
        f32x4 o_[8];
#pragma unroll
        for (int i = 0; i < 4; ++i) { m_[i] = -INFINITY; lsum[i] = 0.f; }
#pragma unroll
        for (int db = 0; db < 8; ++db) o_[db] = (f32x4){0.f, 0.f, 0.f, 0.f};

        stage_load(0);
        __syncthreads();           // prev phase readers done before buf0 overwrite
        stage_write(0);
        if (ntiles > 1) stage_load(1);

        for (int j = 0; j < ntiles; ++j) {
            __syncthreads();                        // buf[j&1] ready; buf[(j+1)&1] free
            if (j + 1 < ntiles) stage_write((j + 1) & 1);
            if (j + 2 < ntiles) stage_load(j + 2);  // global loads fly under compute

            if (j <= jmaxw) {
                const int k0 = j * 32;
                const int d  = j & 1;

                // ---- S = Q K^T (pre-scaled) ----
                f32x4 s0 = (f32x4){0.f, 0.f, 0.f, 0.f};
                f32x4 s1 = (f32x4){0.f, 0.f, 0.f, 0.f};
                const int sw = (lo & 7) << 4;
                const char* kbase = (const char*)KS[d];
#pragma unroll
                for (int c = 0; c < 4; ++c) {
                    bf16x8 kf0 = *(const bf16x8*)(kbase + ((lo * 256 + c * 64 + g * 16) ^ sw));
                    bf16x8 kf1 = *(const bf16x8*)(kbase + (((16 + lo) * 256 + c * 64 + g * 16) ^ sw));
                    s0 = __builtin_amdgcn_mfma_f32_16x16x32_bf16(qf[c], kf0, s0, 0, 0, 0);
                    s1 = __builtin_amdgcn_mfma_f32_16x16x32_bf16(qf[c], kf1, s1, 0, 0, 0);
                }

                // ---- online softmax: defer-sum + defer-max(THR=8) ----
                const bool needmask = (k0 + 31) > qw0;
#pragma unroll
                for (int i = 0; i < 4; ++i) {
                    float v0 = s0[i], v1 = s1[i];
                    if (needmask) {
                        const int qi = qw0 + 4 * g + i;
                        if (k0 + lo > qi)      v0 = -INFINITY;
                        if (k0 + 16 + lo > qi) v1 = -INFINITY;
                    }
                    float tm = fmaxf(v0, v1);
                    tm = fmaxf(tm, __shfl_xor(tm, 1));
                    tm = fmaxf(tm, __shfl_xor(tm, 2));
                    tm = fmaxf(tm, __shfl_xor(tm, 4));
                    tm = fmaxf(tm, __shfl_xor(tm, 8));
                    if (__any(tm > m_[i] + 8.0f)) {
                        const float mn = fmaxf(m_[i], tm);
                        const float al = EXP2F(m_[i] - mn);
                        m_[i] = mn;
                        lsum[i] *= al;
#pragma unroll
                        for (int db = 0; db < 8; ++db) o_[db][i] *= al;
                    }
                    const float p0 = EXP2F(v0 - m_[i]);
                    const float p1 = EXP2F(v1 - m_[i]);
                    lsum[i] += p0 + p1;              // per-lane; reduced in epilogue
                    PW[w][(4 * g + i) * PW_STR + lo]      = f2b(p0);
                    PW[w][(4 * g + i) * PW_STR + 16 + lo] = f2b(p1);
                }

                // ---- PV ----
                bf16x8 pf = *(const bf16x8*)(&PW[w][lo * PW_STR + g * 8]);
                const char* vbase = (const char*)VT[d];
                const int swv = (lo & 3) << 4;
#pragma unroll
                for (int db = 0; db < 8; ++db) {
                    bf16x8 vf = *(const bf16x8*)(vbase + (db * 16 + lo) * 64 + ((g * 16) ^ swv));
                    o_[db] = __builtin_amdgcn_mfma_f32_16x16x32_bf16(pf, vf, o_[db], 0, 0, 0);
                }
            }
        }

        // ---- epilogue: reduce lsum across the 16-lane row group, store ----
#pragma unroll
        for (int i = 0; i < 4; ++i) {
            float rs = lsum[i];
            rs += __shfl_xor(rs, 1);
            rs += __shfl_xor(rs, 2);
            rs += __shfl_xor(rs, 4);
            rs += __shfl_xor(rs, 8);
            const float inv = 1.0f / rs;
            float* op = O + ((size_t)(b * SEQ_ + qw0 + 4 * g + i)) * (H_ * DV_) + h * DV_ + lo;
#pragma unroll
            for (int db = 0; db < 8; ++db) op[db * 16] = o_[db][i] * inv;
        }
    }
}

extern "C" void kernel_launch(void* const* d_in, const int* in_sizes, int n_in,
                              void* d_out, int out_size, void* d_ws, size_t ws_size,
                              hipStream_t stream) {
    const float* Q = (const float*)d_in[0];
    const float* K = (const float*)d_in[1];
    const float* V = (const float*)d_in[2];
    float* Out = (float*)d_out;
    attn_fwd<<<dim3(1024), dim3(256), 0, stream>>>(Q, K, V, Out);
}

// Round 4
// 604.806 us; speedup vs baseline: 1.1323x; 1.1323x over previous
//
#include <hip/hip_runtime.h>
#include <hip/hip_bf16.h>

#define H_   32
#define KVH_ 8
#define D_   128
#define DV_  128
#define SEQ_ 1024
#define QKD  (H_*D_)     // 4096 floats per token row of Q
#define KVD  (KVH_*D_)   // 1024 floats per token row of K/V
#define CS_  (0.08838834764831845f * 1.4426950408889634f)  // SCALE*log2(e), folded into Q

typedef __attribute__((ext_vector_type(8))) short bf16x8;
typedef __attribute__((ext_vector_type(4))) float f32x4;
typedef __attribute__((ext_vector_type(4))) unsigned int u32x4;

#if __has_builtin(__builtin_amdgcn_exp2f)
#define EXP2F(x) __builtin_amdgcn_exp2f(x)
#else
#define EXP2F(x) exp2f(x)
#endif

static __device__ __forceinline__ unsigned short f2b(float x) {
    __hip_bfloat16 b = __float2bfloat16(x);
    return __builtin_bit_cast(unsigned short, b);
}
static __device__ __forceinline__ unsigned pk2(float a, float b) {
    return (unsigned)f2b(a) | ((unsigned)f2b(b) << 16);
}

// K tile: [32 rows][128 halfs] linear 256B rows, XOR-swizzled byte^((row&7)<<4)
// V^T tile: [dv=128][stride 40 halfs] (32 k-cols used, +8 pad)
// P per-wave: [q=16][stride 40 halfs]
#define VT_STR 40
#define PW_STR 40

__global__ __launch_bounds__(256, 4)
void attn_fwd(const float* __restrict__ Q, const float* __restrict__ K,
              const float* __restrict__ V, float* __restrict__ O) {
    __shared__ __align__(16) unsigned short KS[32 * 128];
    __shared__ __align__(16) unsigned short VT[DV_ * VT_STR];
    __shared__ __align__(16) unsigned short PW[4][16 * PW_STR];

    // grid = B(4) * H(32) * pair(8) = 1024; XCD-bijective swizzle (1024%8==0)
    const int bid = ((int)blockIdx.x & 7) * 128 + ((int)blockIdx.x >> 3);
    const int p   = bid & 7;           // pair: q-tiles {p, 15-p} -> uniform 34 k-tiles/block
    const int h   = (bid >> 3) & 31;
    const int b   = bid >> 8;
    const int kvh = h >> 2;

    const int tid = threadIdx.x;
    const int w   = tid >> 6;
    const int l   = tid & 63;
    const int lo  = l & 15;
    const int g   = l >> 4;

    const int kr_ = tid >> 3;          // K stage row 0..31
    const int kq_ = tid & 7;           // K stage 16-float quarter
    const int sdv = tid & 127;         // V stage dv column
    const int skh = tid >> 7;          // V stage k-half (0/1)

    const float* Kb = K + ((size_t)(b * SEQ_)) * KVD + kvh * D_;
    const float* Vb = V + ((size_t)(b * SEQ_)) * KVD + kvh * DV_;

    float4 kpre[4];
    float  vpre[16];

    auto stage_load = [&](int t) {   // issue global loads for k-tile t -> regs
        const float* kp = Kb + ((size_t)(t * 32 + kr_)) * KVD + kq_ * 16;
        kpre[0] = *(const float4*)(kp);
        kpre[1] = *(const float4*)(kp + 4);
        kpre[2] = *(const float4*)(kp + 8);
        kpre[3] = *(const float4*)(kp + 12);
        const float* vp = Vb + ((size_t)(t * 32 + skh * 16)) * KVD + sdv;
#pragma unroll
        for (int e = 0; e < 16; ++e) vpre[e] = vp[(size_t)e * KVD];
    };
    auto stage_write = [&]() {       // cvt + LDS write of the prefetched tile
        const int kb0 = (kr_ * 256 + kq_ * 32) ^ ((kr_ & 7) << 4);
        const int kb1 = (kr_ * 256 + kq_ * 32 + 16) ^ ((kr_ & 7) << 4);
        u32x4 ka = { pk2(kpre[0].x, kpre[0].y), pk2(kpre[0].z, kpre[0].w),
                     pk2(kpre[1].x, kpre[1].y), pk2(kpre[1].z, kpre[1].w) };
        u32x4 kb = { pk2(kpre[2].x, kpre[2].y), pk2(kpre[2].z, kpre[2].w),
                     pk2(kpre[3].x, kpre[3].y), pk2(kpre[3].z, kpre[3].w) };
        *(u32x4*)((char*)KS + kb0) = ka;
        *(u32x4*)((char*)KS + kb1) = kb;
        u32x4 v0 = { pk2(vpre[0], vpre[1]),  pk2(vpre[2], vpre[3]),
                     pk2(vpre[4], vpre[5]),  pk2(vpre[6], vpre[7]) };
        u32x4 v1 = { pk2(vpre[8], vpre[9]),  pk2(vpre[10], vpre[11]),
                     pk2(vpre[12], vpre[13]), pk2(vpre[14], vpre[15]) };
        *(u32x4*)(&VT[sdv * VT_STR + skh * 16])     = v0;
        *(u32x4*)(&VT[sdv * VT_STR + skh * 16 + 8]) = v1;
    };

#pragma unroll 1
    for (int ph = 0; ph < 2; ++ph) {
        const int qt     = ph ? (15 - p) : p;
        const int ntiles = 2 * qt + 2;
        const int qw0    = qt * 64 + w * 16;
        const int jmaxw  = (qw0 + 15) >> 5;

        // Q fragments pre-scaled by SCALE*log2(e): row = lo, d = 32c + 8g + e
        const float* Qb = Q + ((size_t)(b * SEQ_ + qw0 + lo)) * QKD + h * D_;
        bf16x8 qf[4];
#pragma unroll
        for (int c = 0; c < 4; ++c) {
            const float* qp = Qb + c * 32 + g * 8;
            float4 x0 = *(const float4*)(qp);
            float4 x1 = *(const float4*)(qp + 4);
            bf16x8 f;
            f[0] = f2b(x0.x * CS_); f[1] = f2b(x0.y * CS_);
            f[2] = f2b(x0.z * CS_); f[3] = f2b(x0.w * CS_);
            f[4] = f2b(x1.x * CS_); f[5] = f2b(x1.y * CS_);
            f[6] = f2b(x1.z * CS_); f[7] = f2b(x1.w * CS_);
            qf[c] = f;
        }

        float m_[4], lsum[4];
        f32x4 o_[8];
#pragma unroll
        for (int i = 0; i < 4; ++i) { m_[i] = -INFINITY; lsum[i] = 0.f; }
#pragma unroll
        for (int db = 0; db < 8; ++db) o_[db] = (f32x4){0.f, 0.f, 0.f, 0.f};

        stage_load(0);

#pragma unroll 1
        for (int j = 0; j < ntiles; ++j) {
            __syncthreads();                       // prev tile's LDS readers done
            stage_write();
            __syncthreads();                       // tile visible to all waves
            if (j + 1 < ntiles) stage_load(j + 1); // loads fly under compute
            if (j <= jmaxw) {
                const int k0 = j * 32;

                // ---- S = Q K^T (pre-scaled) ----
                f32x4 s0 = (f32x4){0.f, 0.f, 0.f, 0.f};
                f32x4 s1 = (f32x4){0.f, 0.f, 0.f, 0.f};
                const int sw = (lo & 7) << 4;
#pragma unroll
                for (int c = 0; c < 4; ++c) {
                    bf16x8 kf0 = *(const bf16x8*)((const char*)KS +
                                   ((lo * 256 + c * 64 + g * 16) ^ sw));
                    bf16x8 kf1 = *(const bf16x8*)((const char*)KS +
                                   (((16 + lo) * 256 + c * 64 + g * 16) ^ sw));
                    s0 = __builtin_amdgcn_mfma_f32_16x16x32_bf16(qf[c], kf0, s0, 0, 0, 0);
                    s1 = __builtin_amdgcn_mfma_f32_16x16x32_bf16(qf[c], kf1, s1, 0, 0, 0);
                }

                // ---- online softmax: defer-sum + defer-max(THR=8 in log2 units) ----
                const bool needmask = (k0 + 31) > qw0;
#pragma unroll
                for (int i = 0; i < 4; ++i) {
                    float v0 = s0[i], v1 = s1[i];
                    if (needmask) {
                        const int qi = qw0 + 4 * g + i;
                        if (k0 + lo > qi)      v0 = -INFINITY;
                        if (k0 + 16 + lo > qi) v1 = -INFINITY;
                    }
                    float tm = fmaxf(v0, v1);
                    tm = fmaxf(tm, __shfl_xor(tm, 1));
                    tm = fmaxf(tm, __shfl_xor(tm, 2));
                    tm = fmaxf(tm, __shfl_xor(tm, 4));
                    tm = fmaxf(tm, __shfl_xor(tm, 8));
                    if (__any(tm > m_[i] + 8.0f)) {
                        const float mn = fmaxf(m_[i], tm);
                        const float al = EXP2F(m_[i] - mn);
                        m_[i] = mn;
                        lsum[i] *= al;
#pragma unroll
                        for (int db = 0; db < 8; ++db) o_[db][i] *= al;
                    }
                    const float p0 = EXP2F(v0 - m_[i]);
                    const float p1 = EXP2F(v1 - m_[i]);
                    lsum[i] += p0 + p1;              // per-lane; reduced in epilogue
                    PW[w][(4 * g + i) * PW_STR + lo]      = f2b(p0);
                    PW[w][(4 * g + i) * PW_STR + 16 + lo] = f2b(p1);
                }

                // ---- PV ----
                bf16x8 pf = *(const bf16x8*)(&PW[w][lo * PW_STR + g * 8]);
#pragma unroll
                for (int db = 0; db < 8; ++db) {
                    bf16x8 vf = *(const bf16x8*)(&VT[(db * 16 + lo) * VT_STR + g * 8]);
                    o_[db] = __builtin_amdgcn_mfma_f32_16x16x32_bf16(pf, vf, o_[db], 0, 0, 0);
                }
            }
        }

        // ---- epilogue: reduce lsum across 16-lane row group, normalize, store ----
#pragma unroll
        for (int i = 0; i < 4; ++i) {
            float rs = lsum[i];
            rs += __shfl_xor(rs, 1);
            rs += __shfl_xor(rs, 2);
            rs += __shfl_xor(rs, 4);
            rs += __shfl_xor(rs, 8);
            const float inv = 1.0f / rs;
            float* op = O + ((size_t)(b * SEQ_ + qw0 + 4 * g + i)) * (H_ * DV_) + h * DV_ + lo;
#pragma unroll
            for (int db = 0; db < 8; ++db) op[db * 16] = o_[db][i] * inv;
        }
    }
}

extern "C" void kernel_launch(void* const* d_in, const int* in_sizes, int n_in,
                              void* d_out, int out_size, void* d_ws, size_t ws_size,
                              hipStream_t stream) {
    const float* Q = (const float*)d_in[0];
    const float* K = (const float*)d_in[1];
    const float* V = (const float*)d_in[2];
    float* Out = (float*)d_out;
    attn_fwd<<<dim3(1024), dim3(256), 0, stream>>>(Q, K, V, Out);
}

// Round 5
// 175.948 us; speedup vs baseline: 3.8921x; 3.4374x over previous
//
#include <hip/hip_runtime.h>
#include <hip/hip_bf16.h>

#define H_   32
#define KVH_ 8
#define D_   128
#define DV_  128
#define SEQ_ 1024
#define QKD  (H_*D_)     // 4096 floats per token row of Q
#define KVD  (KVH_*D_)   // 1024 floats per token row of K/V
#define CS_  (0.08838834764831845f * 1.4426950408889634f)  // SCALE*log2(e), folded into Q

typedef __attribute__((ext_vector_type(8))) short bf16x8;
typedef __attribute__((ext_vector_type(4))) float f32x4;
typedef __attribute__((ext_vector_type(4))) unsigned int u32x4;

#if __has_builtin(__builtin_amdgcn_exp2f)
#define EXP2F(x) __builtin_amdgcn_exp2f(x)
#else
#define EXP2F(x) exp2f(x)
#endif

static __device__ __forceinline__ unsigned short f2b(float x) {
    __hip_bfloat16 b = __float2bfloat16(x);
    return __builtin_bit_cast(unsigned short, b);
}
static __device__ __forceinline__ unsigned pk2(float a, float b) {
    return (unsigned)f2b(a) | ((unsigned)f2b(b) << 16);
}

// K tile: [32 rows][128 halfs] linear 256B rows, XOR-swizzled byte^((row&7)<<4)
// V^T tile: [dv=128][stride 40 halfs] (32 k-cols used, +8 pad)
// P per-wave: [q=16][stride 40 halfs]
#define VT_STR 40
#define PW_STR 40

__global__ __launch_bounds__(256, 4)
void attn_fwd(const float* __restrict__ Q, const float* __restrict__ K,
              const float* __restrict__ V, float* __restrict__ O) {
    __shared__ __align__(16) unsigned short KS[32 * 128];
    __shared__ __align__(16) unsigned short VT[DV_ * VT_STR];
    __shared__ __align__(16) unsigned short PW[4][16 * PW_STR];

    // grid = B(4) * H(32) * pair(8) = 1024; XCD-bijective swizzle (1024%8==0)
    const int bid = ((int)blockIdx.x & 7) * 128 + ((int)blockIdx.x >> 3);
    const int p   = bid & 7;           // pair: q-tiles {p, 15-p} -> uniform 34 k-tiles/block
    const int h   = (bid >> 3) & 31;
    const int b   = bid >> 8;
    const int kvh = h >> 2;

    const int tid = threadIdx.x;
    const int w   = tid >> 6;
    const int l   = tid & 63;
    const int lo  = l & 15;
    const int g   = l >> 4;

    const int kr_ = tid >> 3;          // K stage row 0..31
    const int kq_ = tid & 7;           // K stage 16-float quarter
    const int sdv = tid & 127;         // V stage dv column
    const int skh = tid >> 7;          // V stage k-half (0/1)

    const float* Kb = K + ((size_t)(b * SEQ_)) * KVD + kvh * D_;
    const float* Vb = V + ((size_t)(b * SEQ_)) * KVD + kvh * DV_;

    float4 kpre[4];
    float  vpre[16];

    auto stage_load = [&](int t) {   // issue global loads for k-tile t -> regs
        const float* kp = Kb + ((size_t)(t * 32 + kr_)) * KVD + kq_ * 16;
        kpre[0] = *(const float4*)(kp);
        kpre[1] = *(const float4*)(kp + 4);
        kpre[2] = *(const float4*)(kp + 8);
        kpre[3] = *(const float4*)(kp + 12);
        const float* vp = Vb + ((size_t)(t * 32 + skh * 16)) * KVD + sdv;
#pragma unroll
        for (int e = 0; e < 16; ++e) vpre[e] = vp[(size_t)e * KVD];
    };
    auto stage_write = [&]() {       // cvt + LDS write of the prefetched tile
        const int kb0 = (kr_ * 256 + kq_ * 32) ^ ((kr_ & 7) << 4);
        const int kb1 = (kr_ * 256 + kq_ * 32 + 16) ^ ((kr_ & 7) << 4);
        u32x4 ka = { pk2(kpre[0].x, kpre[0].y), pk2(kpre[0].z, kpre[0].w),
                     pk2(kpre[1].x, kpre[1].y), pk2(kpre[1].z, kpre[1].w) };
        u32x4 kb = { pk2(kpre[2].x, kpre[2].y), pk2(kpre[2].z, kpre[2].w),
                     pk2(kpre[3].x, kpre[3].y), pk2(kpre[3].z, kpre[3].w) };
        *(u32x4*)((char*)KS + kb0) = ka;
        *(u32x4*)((char*)KS + kb1) = kb;
        u32x4 v0 = { pk2(vpre[0], vpre[1]),  pk2(vpre[2], vpre[3]),
                     pk2(vpre[4], vpre[5]),  pk2(vpre[6], vpre[7]) };
        u32x4 v1 = { pk2(vpre[8], vpre[9]),  pk2(vpre[10], vpre[11]),
                     pk2(vpre[12], vpre[13]), pk2(vpre[14], vpre[15]) };
        *(u32x4*)(&VT[sdv * VT_STR + skh * 16])     = v0;
        *(u32x4*)(&VT[sdv * VT_STR + skh * 16 + 8]) = v1;
    };

#pragma unroll 1
    for (int ph = 0; ph < 2; ++ph) {
        const int qt     = ph ? (15 - p) : p;
        const int ntiles = 2 * qt + 2;
        const int qw0    = qt * 64 + w * 16;
        const int jmaxw  = (qw0 + 15) >> 5;

        // Q fragments pre-scaled by SCALE*log2(e): row = lo, d = 32c + 8g + e
        const float* Qb = Q + ((size_t)(b * SEQ_ + qw0 + lo)) * QKD + h * D_;
        bf16x8 qf[4];
#pragma unroll
        for (int c = 0; c < 4; ++c) {
            const float* qp = Qb + c * 32 + g * 8;
            float4 x0 = *(const float4*)(qp);
            float4 x1 = *(const float4*)(qp + 4);
            bf16x8 f;
            f[0] = f2b(x0.x * CS_); f[1] = f2b(x0.y * CS_);
            f[2] = f2b(x0.z * CS_); f[3] = f2b(x0.w * CS_);
            f[4] = f2b(x1.x * CS_); f[5] = f2b(x1.y * CS_);
            f[6] = f2b(x1.z * CS_); f[7] = f2b(x1.w * CS_);
            qf[c] = f;
        }

        float m_[4], lsum[4];
        f32x4 o_[8];
#pragma unroll
        for (int i = 0; i < 4; ++i) { m_[i] = -INFINITY; lsum[i] = 0.f; }
#pragma unroll
        for (int db = 0; db < 8; ++db) o_[db] = (f32x4){0.f, 0.f, 0.f, 0.f};

        stage_load(0);

        for (int j = 0; j < ntiles; ++j) {
            __syncthreads();                       // prev tile's LDS readers done
            stage_write();
            __syncthreads();                       // tile visible to all waves
            if (j + 1 < ntiles) stage_load(j + 1); // loads fly under compute
            if (j <= jmaxw) {
                const int k0 = j * 32;

                // ---- S = Q K^T (pre-scaled, log2 units) ----
                f32x4 s0 = (f32x4){0.f, 0.f, 0.f, 0.f};
                f32x4 s1 = (f32x4){0.f, 0.f, 0.f, 0.f};
                const int sw = (lo & 7) << 4;
#pragma unroll
                for (int c = 0; c < 4; ++c) {
                    bf16x8 kf0 = *(const bf16x8*)((const char*)KS +
                                   ((lo * 256 + c * 64 + g * 16) ^ sw));
                    bf16x8 kf1 = *(const bf16x8*)((const char*)KS +
                                   (((16 + lo) * 256 + c * 64 + g * 16) ^ sw));
                    s0 = __builtin_amdgcn_mfma_f32_16x16x32_bf16(qf[c], kf0, s0, 0, 0, 0);
                    s1 = __builtin_amdgcn_mfma_f32_16x16x32_bf16(qf[c], kf1, s1, 0, 0, 0);
                }

                // ---- online softmax: branchless rescale + defer-sum ----
                const bool needmask = (k0 + 31) > qw0;
#pragma unroll
                for (int i = 0; i < 4; ++i) {
                    float v0 = s0[i], v1 = s1[i];
                    if (needmask) {
                        const int qi = qw0 + 4 * g + i;
                        if (k0 + lo > qi)      v0 = -INFINITY;
                        if (k0 + 16 + lo > qi) v1 = -INFINITY;
                    }
                    float tm = fmaxf(v0, v1);
                    tm = fmaxf(tm, __shfl_xor(tm, 1));
                    tm = fmaxf(tm, __shfl_xor(tm, 2));
                    tm = fmaxf(tm, __shfl_xor(tm, 4));
                    tm = fmaxf(tm, __shfl_xor(tm, 8));
                    const float mn = fmaxf(m_[i], tm);
                    const float al = EXP2F(m_[i] - mn);
                    m_[i] = mn;
                    const float p0 = EXP2F(v0 - mn);
                    const float p1 = EXP2F(v1 - mn);
                    lsum[i] = lsum[i] * al + (p0 + p1);   // per-lane; epilogue reduce
#pragma unroll
                    for (int db = 0; db < 8; ++db) o_[db][i] *= al;
                    PW[w][(4 * g + i) * PW_STR + lo]      = f2b(p0);
                    PW[w][(4 * g + i) * PW_STR + 16 + lo] = f2b(p1);
                }

                // ---- PV ----
                bf16x8 pf = *(const bf16x8*)(&PW[w][lo * PW_STR + g * 8]);
#pragma unroll
                for (int db = 0; db < 8; ++db) {
                    bf16x8 vf = *(const bf16x8*)(&VT[(db * 16 + lo) * VT_STR + g * 8]);
                    o_[db] = __builtin_amdgcn_mfma_f32_16x16x32_bf16(pf, vf, o_[db], 0, 0, 0);
                }
            }
        }

        // ---- epilogue: reduce lsum over 16-lane group, normalize, store ----
#pragma unroll
        for (int i = 0; i < 4; ++i) {
            float rs = lsum[i];
            rs += __shfl_xor(rs, 1);
            rs += __shfl_xor(rs, 2);
            rs += __shfl_xor(rs, 4);
            rs += __shfl_xor(rs, 8);
            const float inv = 1.0f / rs;
            float* op = O + ((size_t)(b * SEQ_ + qw0 + 4 * g + i)) * (H_ * DV_) + h * DV_ + lo;
#pragma unroll
            for (int db = 0; db < 8; ++db) op[db * 16] = o_[db][i] * inv;
        }
    }
}

extern "C" void kernel_launch(void* const* d_in, const int* in_sizes, int n_in,
                              void* d_out, int out_size, void* d_ws, size_t ws_size,
                              hipStream_t stream) {
    const float* Q = (const float*)d_in[0];
    const float* K = (const float*)d_in[1];
    const float* V = (const float*)d_in[2];
    float* Out = (float*)d_out;
    attn_fwd<<<dim3(1024), dim3(256), 0, stream>>>(Q, K, V, Out);
}

// Round 6
// 108.409 us; speedup vs baseline: 6.3168x; 1.6230x over previous
//
#include <hip/hip_runtime.h>
#include <hip/hip_bf16.h>

#define H_   32
#define KVH_ 8
#define D_   128
#define DV_  128
#define SEQ_ 1024
#define QKD  (H_*D_)
#define KVD  (KVH_*D_)
#define CS_  (0.08838834764831845f * 1.4426950408889634f)  // SCALE*log2(e)

typedef __attribute__((ext_vector_type(8))) short bf16x8;
typedef __attribute__((ext_vector_type(8))) unsigned short u16x8;
typedef __attribute__((ext_vector_type(4))) float f32x4;
typedef __attribute__((ext_vector_type(4))) unsigned int u32x4;

typedef const __attribute__((address_space(1))) void* gp_t;
typedef __attribute__((address_space(3))) void* lp_t;

#if __has_builtin(__builtin_amdgcn_exp2f)
#define EXP2F(x) __builtin_amdgcn_exp2f(x)
#else
#define EXP2F(x) exp2f(x)
#endif

static __device__ __forceinline__ unsigned short f2b(float x) {
    __hip_bfloat16 b = __float2bfloat16(x);
    return __builtin_bit_cast(unsigned short, b);
}
static __device__ __forceinline__ unsigned pk2(float a, float b) {
    return (unsigned)f2b(a) | ((unsigned)f2b(b) << 16);
}

#define PW_STR 40

// ---------- pre-pass: K f32 [T][KVH*128] -> bf16 [bh][s][128] ----------
__global__ __launch_bounds__(256)
void prep_k(const float* __restrict__ K, unsigned short* __restrict__ Kb) {
    const int gt = blockIdx.x * 256 + threadIdx.x;   // 524288 threads
    const int q  = gt & 15;                          // 8-elem chunk in row
    const int r  = gt >> 4;                          // out row (bh*1024+s)
    const int s  = r & 1023;
    const int bh = r >> 10;
    const int b = bh >> 3, kvh = bh & 7;
    const float* src = K + ((size_t)(b * SEQ_ + s)) * KVD + kvh * D_ + q * 8;
    float4 a = *(const float4*)src;
    float4 c = *(const float4*)(src + 4);
    u32x4 o = { pk2(a.x, a.y), pk2(a.z, a.w), pk2(c.x, c.y), pk2(c.z, c.w) };
    *(u32x4*)(Kb + (size_t)r * 128 + q * 8) = o;
}

// ---------- pre-pass: V f32 [T][KVH*128] -> bf16 transposed [bh][dv][s] ----------
__global__ __launch_bounds__(256)
void prep_v(const float* __restrict__ V, unsigned short* __restrict__ Vt) {
    const int gt = blockIdx.x * 256 + threadIdx.x;   // 524288 threads
    const int dv = gt & 127;
    const int sc = (gt >> 7) & 127;                  // 8-s chunk
    const int bh = gt >> 14;
    const int b = bh >> 3, kvh = bh & 7;
    const float* src = V + ((size_t)(b * SEQ_ + sc * 8)) * KVD + kvh * DV_ + dv;
    unsigned short e[8];
#pragma unroll
    for (int i = 0; i < 8; ++i) e[i] = f2b(src[(size_t)i * KVD]);
    u16x8 o = { e[0], e[1], e[2], e[3], e[4], e[5], e[6], e[7] };
    *(u16x8*)(Vt + ((size_t)bh * 128 + dv) * SEQ_ + sc * 8) = o;
}

// ---------- attention ----------
// KS tile: [32 k][128 d] bf16, 256B rows, chunk-swizzle slot^=(row&7)  (read XOR (lo&7)<<4)
// VT tile: [128 dv][32 k] bf16, 64B rows,  chunk-swizzle slot^=((dv>>1)&3) (read XOR ((lo>>1)&3)<<4)
// Both staged via global_load_lds(16B) with the inverse swizzle applied to the SOURCE address.
__global__ __launch_bounds__(256, 4)
void attn_fwd(const float* __restrict__ Q,
              const unsigned short* __restrict__ Kb,
              const unsigned short* __restrict__ Vt,
              float* __restrict__ O) {
    __shared__ __align__(16) unsigned short KS[2][32 * 128];
    __shared__ __align__(16) unsigned short VT[2][128 * 32];
    __shared__ __align__(16) unsigned short PW[4][16 * PW_STR];

    const int bid = ((int)blockIdx.x & 7) * 128 + ((int)blockIdx.x >> 3);
    const int p   = bid & 7;           // pair {p, 15-p}: uniform 34 k-tiles/block
    const int h   = (bid >> 3) & 31;
    const int b   = bid >> 8;
    const int kvh = h >> 2;
    const int bh  = b * 8 + kvh;

    const int tid = threadIdx.x;
    const int w   = tid >> 6;
    const int l   = tid & 63;
    const int lo  = l & 15;
    const int g   = l >> 4;

    // per-lane pre-swizzled source addresses (wave w issues LDS chunks c0, c1)
    const int c0 = w * 128 + l;
    const int c1 = c0 + 64;
    const int kr0 = c0 >> 4, ks0 = c0 & 15;
    const int kr1 = c1 >> 4, ks1 = c1 & 15;
    const int offk0 = kr0 * 256 + (((ks0 & 8) | ((ks0 & 7) ^ (kr0 & 7))) << 4);
    const int offk1 = kr1 * 256 + (((ks1 & 8) | ((ks1 & 7) ^ (kr1 & 7))) << 4);
    const int offv0 = (c0 >> 2) * 2048 + (((c0 & 3) ^ ((c0 >> 3) & 3)) << 4);
    const int offv1 = (c1 >> 2) * 2048 + (((c1 & 3) ^ ((c1 >> 3) & 3)) << 4);

    const char* KbH = (const char*)Kb + (size_t)bh * 262144;  // 1024*128*2
    const char* VtH = (const char*)Vt + (size_t)bh * 262144;
    const char* ksrc0 = KbH + offk0;
    const char* ksrc1 = KbH + offk1;
    const char* vsrc0 = VtH + offv0;
    const char* vsrc1 = VtH + offv1;

    auto issue = [&](int t, int dsel) {   // stage k-tile t into buffer dsel
        char* ks = (char*)KS[dsel] + w * 2048;
        char* vs = (char*)VT[dsel] + w * 2048;
        const size_t ko = (size_t)t * 8192;   // 32 rows * 256B
        const size_t vo = (size_t)t * 64;     // 32 k * 2B within each dv row
        __builtin_amdgcn_global_load_lds((gp_t)(ksrc0 + ko), (lp_t)ks,          16, 0, 0);
        __builtin_amdgcn_global_load_lds((gp_t)(ksrc1 + ko), (lp_t)(ks + 1024), 16, 0, 0);
        __builtin_amdgcn_global_load_lds((gp_t)(vsrc0 + vo), (lp_t)vs,          16, 0, 0);
        __builtin_amdgcn_global_load_lds((gp_t)(vsrc1 + vo), (lp_t)(vs + 1024), 16, 0, 0);
    };

#pragma unroll 1
    for (int ph = 0; ph < 2; ++ph) {
        const int qt     = ph ? (15 - p) : p;
        const int ntiles = 2 * qt + 2;
        const int qw0    = qt * 64 + w * 16;
        const int jmaxw  = (qw0 + 15) >> 5;

        // Q fragments pre-scaled by SCALE*log2(e): row = lo, d = 32c + 8g + e
        const float* Qb = Q + ((size_t)(b * SEQ_ + qw0 + lo)) * QKD + h * D_;
        bf16x8 qf[4];
#pragma unroll
        for (int c = 0; c < 4; ++c) {
            const float* qp = Qb + c * 32 + g * 8;
            float4 x0 = *(const float4*)(qp);
            float4 x1 = *(const float4*)(qp + 4);
            bf16x8 f;
            f[0] = f2b(x0.x * CS_); f[1] = f2b(x0.y * CS_);
            f[2] = f2b(x0.z * CS_); f[3] = f2b(x0.w * CS_);
            f[4] = f2b(x1.x * CS_); f[5] = f2b(x1.y * CS_);
            f[6] = f2b(x1.z * CS_); f[7] = f2b(x1.w * CS_);
            qf[c] = f;
        }

        float m_[4], lsum[4];
        f32x4 o_[8];
#pragma unroll
        for (int i = 0; i < 4; ++i) { m_[i] = -INFINITY; lsum[i] = 0.f; }
#pragma unroll
        for (int db = 0; db < 8; ++db) o_[db] = (f32x4){0.f, 0.f, 0.f, 0.f};

        __syncthreads();               // prior phase's readers done with both buffers
        issue(0, 0);

        for (int j = 0; j < ntiles; ++j) {
            __syncthreads();           // tile j landed (vmcnt drained); buf[(j+1)&1] free
            if (j + 1 < ntiles) issue(j + 1, (j + 1) & 1);   // flies under compute
            if (j <= jmaxw) {
                const int k0 = j * 32;
                const int d  = j & 1;

                // ---- S = Q K^T (pre-scaled, log2 units) ----
                f32x4 s0 = (f32x4){0.f, 0.f, 0.f, 0.f};
                f32x4 s1 = (f32x4){0.f, 0.f, 0.f, 0.f};
                const int sw = (lo & 7) << 4;
                const char* kbase = (const char*)KS[d];
                __builtin_amdgcn_s_setprio(1);
#pragma unroll
                for (int c = 0; c < 4; ++c) {
                    bf16x8 kf0 = *(const bf16x8*)(kbase + ((lo * 256 + c * 64 + g * 16) ^ sw));
                    bf16x8 kf1 = *(const bf16x8*)(kbase + (((16 + lo) * 256 + c * 64 + g * 16) ^ sw));
                    s0 = __builtin_amdgcn_mfma_f32_16x16x32_bf16(qf[c], kf0, s0, 0, 0, 0);
                    s1 = __builtin_amdgcn_mfma_f32_16x16x32_bf16(qf[c], kf1, s1, 0, 0, 0);
                }
                __builtin_amdgcn_s_setprio(0);

                // ---- online softmax: branchless rescale + defer-sum ----
                const bool needmask = (k0 + 31) > qw0;
#pragma unroll
                for (int i = 0; i < 4; ++i) {
                    float v0 = s0[i], v1 = s1[i];
                    if (needmask) {
                        const int qi = qw0 + 4 * g + i;
                        if (k0 + lo > qi)      v0 = -INFINITY;
                        if (k0 + 16 + lo > qi) v1 = -INFINITY;
                    }
                    float tm = fmaxf(v0, v1);
                    tm = fmaxf(tm, __shfl_xor(tm, 1));
                    tm = fmaxf(tm, __shfl_xor(tm, 2));
                    tm = fmaxf(tm, __shfl_xor(tm, 4));
                    tm = fmaxf(tm, __shfl_xor(tm, 8));
                    const float mn = fmaxf(m_[i], tm);
                    const float al = EXP2F(m_[i] - mn);
                    m_[i] = mn;
                    const float p0 = EXP2F(v0 - mn);
                    const float p1 = EXP2F(v1 - mn);
                    lsum[i] = lsum[i] * al + (p0 + p1);
#pragma unroll
                    for (int db = 0; db < 8; ++db) o_[db][i] *= al;
                    PW[w][(4 * g + i) * PW_STR + lo]      = f2b(p0);
                    PW[w][(4 * g + i) * PW_STR + 16 + lo] = f2b(p1);
                }

                // ---- PV ----
                bf16x8 pf = *(const bf16x8*)(&PW[w][lo * PW_STR + g * 8]);
                const char* vbase = (const char*)VT[d];
                const int swv = ((lo >> 1) & 3) << 4;
                __builtin_amdgcn_s_setprio(1);
#pragma unroll
                for (int db = 0; db < 8; ++db) {
                    bf16x8 vf = *(const bf16x8*)(vbase + (db * 16 + lo) * 64 + ((g * 16) ^ swv));
                    o_[db] = __builtin_amdgcn_mfma_f32_16x16x32_bf16(pf, vf, o_[db], 0, 0, 0);
                }
                __builtin_amdgcn_s_setprio(0);
            }
        }

        // ---- epilogue ----
#pragma unroll
        for (int i = 0; i < 4; ++i) {
            float rs = lsum[i];
            rs += __shfl_xor(rs, 1);
            rs += __shfl_xor(rs, 2);
            rs += __shfl_xor(rs, 4);
            rs += __shfl_xor(rs, 8);
            const float inv = 1.0f / rs;
            float* op = O + ((size_t)(b * SEQ_ + qw0 + 4 * g + i)) * (H_ * DV_) + h * DV_ + lo;
#pragma unroll
            for (int db = 0; db < 8; ++db) op[db * 16] = o_[db][i] * inv;
        }
    }
}

extern "C" void kernel_launch(void* const* d_in, const int* in_sizes, int n_in,
                              void* d_out, int out_size, void* d_ws, size_t ws_size,
                              hipStream_t stream) {
    const float* Q = (const float*)d_in[0];
    const float* K = (const float*)d_in[1];
    const float* V = (const float*)d_in[2];
    float* Out = (float*)d_out;
    unsigned short* Kb = (unsigned short*)d_ws;                       // 8.39 MB
    unsigned short* Vt = (unsigned short*)((char*)d_ws + 8388608);    // 8.39 MB
    prep_k<<<dim3(2048), dim3(256), 0, stream>>>(K, Kb);
    prep_v<<<dim3(2048), dim3(256), 0, stream>>>(V, Vt);
    attn_fwd<<<dim3(1024), dim3(256), 0, stream>>>(Q, Kb, Vt, Out);
}